// Round 5
// baseline (160.163 us; speedup 1.0000x reference)
//
#include <hip/hip_runtime.h>
#include <math.h>
#include <stdint.h>

// Video Swin shifted-window attention, fully fused, one block per window.
// Round 5: latency attack on the R4 structure (occupancy is capped at 16
// waves/CU by the 156KB per-window LDS footprint):
//  - phase 2: waves 0-11 run their TWO (head,i-tile) tasks interleaved
//    (dual dependency chains: C-prefetch/QK/softmax/PV overlap pairwise)
//  - phase 1: q/k and v tiles merged into one t-loop reusing xf fragments
//  - vT swizzle XOR mask (row>>2)&15 -> v scalar writes bank-conflict-free
//  - s_setprio(1) around QK MFMA cluster

#define LOG2E   1.4426950408889634f
#define MASKNEG (-144.26950408889634f)   // -100 * LOG2E

typedef __attribute__((ext_vector_type(8))) short bf16x8;
typedef __attribute__((ext_vector_type(4))) float f32x4;

__device__ __forceinline__ unsigned short cvt1(float f) {
    __bf16 h = (__bf16)f;
    return __builtin_bit_cast(unsigned short, h);
}
__device__ __forceinline__ unsigned cvt2(float lo, float hi) {
    return (unsigned)cvt1(lo) | ((unsigned)cvt1(hi) << 16);
}

// token region code for the shifted-window mask (WIN=(2,7,7), SHIFT=(1,3,3))
__device__ __forceinline__ int tok_code(int t) {
    int pd = t / 49;
    int r  = t - pd * 49;
    int ph = r / 7;
    int pw = r - ph * 7;
    return (pd >= 1 ? 1 : 0) | (ph >= 4 ? 2 : 0) | (pw >= 4 ? 4 : 0);
}

__device__ __forceinline__ float mterm(unsigned pk, int sh, unsigned ci, unsigned cls) {
    return ((((pk >> sh) & 255u) ^ ci) & cls) ? MASKNEG : 0.f;
}

// XOR-swizzled element offset, [rows][128]-bf16 tiles (16B chunks): q/k/xo
__device__ __forceinline__ int swz(int row, int col) {
    return row * 128 + (((col >> 3) ^ (row & 7)) << 3) + (col & 7);
}
// vT swizzle: XOR with (row>>2) so 4-row-strided scalar writes spread banks
__device__ __forceinline__ int vswz(int row, int col) {
    return row * 128 + ((((col >> 3) ^ (row >> 2)) & 15) << 3) + (col & 7);
}

// ---------------- prep: weights -> bf16, bias tables ----------------
template<bool BIG>
__global__ void prep_kernel(const float* __restrict__ qkv_w,
                            const float* __restrict__ proj_w,
                            const float* __restrict__ rpb_table,
                            const int*   __restrict__ rel_index,
                            unsigned short* __restrict__ wqkv,
                            unsigned short* __restrict__ wproj,
                            void* __restrict__ btab) {
    int tid = blockIdx.x * blockDim.x + threadIdx.x;
    int stride = gridDim.x * blockDim.x;
    for (int i = tid; i < 384 * 128; i += stride) wqkv[i]  = cvt1(qkv_w[i]);
    for (int i = tid; i < 128 * 128; i += stride) wproj[i] = cvt1(proj_w[i]);
    if constexpr (BIG) {
        // bm[cls 8][h 4][i 112][j 112] f32: (bias + mask)*LOG2E; j>=98 -> -inf
        float* bm = (float*)btab;
        for (int idx = tid; idx < 32 * 112 * 112; idx += stride) {
            int ch = idx / 12544; int r = idx - ch * 12544;
            int i  = r / 112;     int j = r - i * 112;
            int cls = ch >> 2, h = ch & 3;
            float v;
            if (i < 98) {
                if (j < 98) {
                    float bias = rpb_table[rel_index[i * 98 + j] * 4 + h];
                    bool  msk  = (((unsigned)tok_code(i) ^ (unsigned)tok_code(j)) & (unsigned)cls) != 0;
                    v = bias * LOG2E + (msk ? MASKNEG : 0.f);
                } else v = -INFINITY;
            } else v = 0.f;
            bm[idx] = v;
        }
    } else {
        unsigned short* biasL = (unsigned short*)btab;
        for (int idx = tid; idx < 4 * 112 * 112; idx += stride) {
            int h = idx / 12544; int r = idx - h * 12544;
            int i = r / 112;     int j = r - i * 112;
            float v;
            if (i < 98) v = (j < 98) ? rpb_table[rel_index[i * 98 + j] * 4 + h] * LOG2E
                                     : -INFINITY;
            else v = 0.f;
            biasL[idx] = cvt1(v);
        }
    }
}

// ---------------- main fused kernel ----------------
template<bool BIG>
__global__ __launch_bounds__(1024)
void swin_main(const float* __restrict__ x,
               const float* __restrict__ qkv_b,
               const float* __restrict__ proj_b,
               const unsigned short* __restrict__ wqkv,
               const unsigned short* __restrict__ wproj,
               const void* __restrict__ btab,
               float* __restrict__ out)
{
    extern __shared__ unsigned short lds[];
    unsigned short* q_lds  = lds;            // [112][128] bf16, swz
    unsigned short* k_lds  = lds + 14336;    // [112][128] swz
    unsigned short* vT_lds = lds + 28672;    // [128][128] vswz (cols 112..127 zero)
    unsigned short* xo_lds = lds + 45056;    // [112][128] swz; x then O
    unsigned short* p_lds  = lds + 59392;    // [16 waves][2 buf][16][40]

    const int b    = blockIdx.x;
    const int tid  = threadIdx.x;
    const int wv   = tid >> 6;    // 0..15
    const int lane = tid & 63;
    const int l4   = lane >> 4;   // 0..3
    const int lc   = lane & 15;   // 0..15

    // zero vT pad cols 112..127 (128 rows x 16 cols; 8B per thread, tid<512)
    if (tid < 512) {
        int row = tid >> 2;
        int c   = 112 + (tid & 3) * 4;
        uint2 z; z.x = 0u; z.y = 0u;
        *(uint2*)(vT_lds + vswz(row, c)) = z;
    }

    // stage x -> xo_lds as bf16 (pad rows 98..111 zeroed)
    {
        const float* xb = x + (size_t)b * 12544;
        for (int idx = tid; idx < 3584; idx += 1024) {
            int tok = idx >> 5;
            int c   = (idx & 31) << 2;
            float4 v;
            if (tok < 98) v = *(const float4*)(xb + tok * 128 + c);
            else { v.x = 0.f; v.y = 0.f; v.z = 0.f; v.w = 0.f; }
            uint2 hv; hv.x = cvt2(v.x, v.y); hv.y = cvt2(v.z, v.w);
            *(uint2*)(xo_lds + swz(tok, c)) = hv;
        }
    }
    __syncthreads();

    // ---- Phase 1 (merged): wave wv owns qkv column-tile ct=wv (q<8, k>=8)
    // and half the t-range of v channel-block vd=(wv>>1)*16; one t-loop
    // reuses the xf fragments for both.
    {
        const int ct = wv;
        const int vd = (wv >> 1) * 16;
        bf16x8 wf[4], wf2[4];
        f32x4  bias, bias2;
        const unsigned short* wrow  = wqkv + (ct * 16 + lc) * 128;
        const unsigned short* wrow2 = wqkv + (256 + vd + lc) * 128;
#pragma unroll
        for (int kt = 0; kt < 4; ++kt) {
            wf[kt]  = *(const bf16x8*)(wrow  + kt * 32 + l4 * 8);
            wf2[kt] = *(const bf16x8*)(wrow2 + kt * 32 + l4 * 8);
        }
#pragma unroll
        for (int r = 0; r < 4; ++r) {
            bias[r]  = qkv_b[ct * 16 + l4 * 4 + r];
            bias2[r] = qkv_b[256 + vd + l4 * 4 + r];
        }
        const bool  isq = (ct < 8);
        const float qs  = 0.17677669529663689f * LOG2E;
        const int t0 = (wv & 1) ? 4 : 0, t1 = (wv & 1) ? 7 : 4;
#pragma unroll
        for (int t = 0; t < 7; ++t) {
            bf16x8 xf[4];
#pragma unroll
            for (int kt = 0; kt < 4; ++kt)
                xf[kt] = *(bf16x8*)(xo_lds + swz(t * 16 + lc, kt * 32 + l4 * 8));
            const int tok = t * 16 + lc;
            f32x4 acc = bias;
#pragma unroll
            for (int kt = 0; kt < 4; ++kt)
                acc = __builtin_amdgcn_mfma_f32_16x16x32_bf16(wf[kt], xf[kt], acc, 0, 0, 0);
            if (isq) {
                uint2 hv; hv.x = cvt2(acc[0] * qs, acc[1] * qs); hv.y = cvt2(acc[2] * qs, acc[3] * qs);
                *(uint2*)(q_lds + swz(tok, ct * 16 + l4 * 4)) = hv;
            } else {
                uint2 hv; hv.x = cvt2(acc[0], acc[1]); hv.y = cvt2(acc[2], acc[3]);
                *(uint2*)(k_lds + swz(tok, (ct - 8) * 16 + l4 * 4)) = hv;
            }
            if (t >= t0 && t < t1) {
                f32x4 acc2 = bias2;
#pragma unroll
                for (int kt = 0; kt < 4; ++kt)
                    acc2 = __builtin_amdgcn_mfma_f32_16x16x32_bf16(wf2[kt], xf[kt], acc2, 0, 0, 0);
                const int rb = vd + l4 * 4;
#pragma unroll
                for (int r = 0; r < 4; ++r)
                    vT_lds[vswz(rb + r, tok)] = cvt1(acc2[r]);
            }
        }
    }
    __syncthreads();

    // ---- Phase 2: 28 (head,i-tile) tasks; waves 0-11 run two interleaved ----
    const int wi  = b & 255;
    const unsigned int cls =
        ((wi >> 6) == 3 ? 1u : 0u) | (((wi >> 3) & 7) == 7 ? 2u : 0u) | ((wi & 7) == 7 ? 4u : 0u);

    unsigned int jcp[7];   // packed region codes (small path only)
    if constexpr (!BIG) {
#pragma unroll
        for (int jt = 0; jt < 7; ++jt) {
            int jb = jt * 16 + l4 * 4;
            unsigned int p = 0;
#pragma unroll
            for (int r = 0; r < 4; ++r) p |= (unsigned)tok_code(jb + r < 98 ? jb + r : 0) << (8 * r);
            jcp[jt] = p;
        }
    }

    unsigned short* myP = p_lds + wv * 1280;   // [2][16][40]
    const int nT = (wv < 12) ? 2 : 1;

    {
        f32x4  s[2][7];
        bf16x8 qf[2];
        int    hh[2], ii[2];

        // C-operand prefetch + q fragments for both tasks (loads overlap)
#pragma unroll
        for (int u = 0; u < 2; ++u) {
            if (u >= nT) continue;
            const int task = wv + (u << 4);
            hh[u] = task / 7;
            ii[u] = (task - hh[u] * 7) * 16 + lc;
            qf[u] = *(bf16x8*)(q_lds + swz(ii[u], hh[u] * 32 + l4 * 8));
            if constexpr (BIG) {
                const float* bmrow = (const float*)btab
                    + ((size_t)((int)cls * 4 + hh[u]) * 112 + ii[u]) * 112;
#pragma unroll
                for (int jt = 0; jt < 7; ++jt)
                    s[u][jt] = *(const f32x4*)(bmrow + jt * 16 + l4 * 4);
            } else {
                const unsigned short* brow = (const unsigned short*)btab + (hh[u] * 112 + ii[u]) * 112;
                const unsigned int ci = (unsigned)tok_code(ii[u] < 98 ? ii[u] : 0);
#pragma unroll
                for (int jt = 0; jt < 7; ++jt) {
                    ushort4 bb = *(const ushort4*)(brow + jt * 16 + l4 * 4);
                    s[u][jt][0] = __builtin_bit_cast(float, (unsigned)bb.x << 16) + mterm(jcp[jt], 0,  ci, cls);
                    s[u][jt][1] = __builtin_bit_cast(float, (unsigned)bb.y << 16) + mterm(jcp[jt], 8,  ci, cls);
                    s[u][jt][2] = __builtin_bit_cast(float, (unsigned)bb.z << 16) + mterm(jcp[jt], 16, ci, cls);
                    s[u][jt][3] = __builtin_bit_cast(float, (unsigned)bb.w << 16) + mterm(jcp[jt], 24, ci, cls);
                }
            }
        }

        // QK^T for both tasks (independent MFMA chains)
        __builtin_amdgcn_s_setprio(1);
#pragma unroll
        for (int u = 0; u < 2; ++u) {
            if (u >= nT) continue;
#pragma unroll
            for (int jt = 0; jt < 7; ++jt) {
                bf16x8 kfrag = *(bf16x8*)(k_lds + swz(jt * 16 + lc, hh[u] * 32 + l4 * 8));
                s[u][jt] = __builtin_amdgcn_mfma_f32_16x16x32_bf16(kfrag, qf[u], s[u][jt], 0, 0, 0);
            }
        }
        __builtin_amdgcn_s_setprio(0);

        // softmax max for both tasks
        float mx[2];
#pragma unroll
        for (int u = 0; u < 2; ++u) {
            if (u >= nT) continue;
            float m = -INFINITY;
#pragma unroll
            for (int jt = 0; jt < 7; ++jt)
                m = fmaxf(m, fmaxf(fmaxf(s[u][jt][0], s[u][jt][1]), fmaxf(s[u][jt][2], s[u][jt][3])));
            m = fmaxf(m, __shfl_xor(m, 16));
            m = fmaxf(m, __shfl_xor(m, 32));
            mx[u] = m;
        }

        // exp + pack to bf16 dwords, and row-sums
        uint2 pp[2][8];
        float ls[2];
#pragma unroll
        for (int u = 0; u < 2; ++u) {
            if (u >= nT) continue;
            float l = 0.f;
#pragma unroll
            for (int jt = 0; jt < 7; ++jt) {
                float p0 = exp2f(s[u][jt][0] - mx[u]);
                float p1 = exp2f(s[u][jt][1] - mx[u]);
                float p2 = exp2f(s[u][jt][2] - mx[u]);
                float p3 = exp2f(s[u][jt][3] - mx[u]);
                l += (p0 + p1) + (p2 + p3);
                pp[u][jt].x = cvt2(p0, p1);
                pp[u][jt].y = cvt2(p2, p3);
            }
            pp[u][7].x = 0u; pp[u][7].y = 0u;
            l += __shfl_xor(l, 16);
            l += __shfl_xor(l, 32);
            ls[u] = l;
        }

        // PV per task: P chunk store -> b64 read -> 2 MFMA (DS in-order per wave)
#pragma unroll
        for (int u = 0; u < 2; ++u) {
            if (u >= nT) continue;
            f32x4 o0 = {0.f,0.f,0.f,0.f}, o1 = {0.f,0.f,0.f,0.f};
#pragma unroll
            for (int jt4 = 0; jt4 < 4; ++jt4) {
                unsigned short* pb = myP + (jt4 & 1) * 640;
                *(uint2*)(pb + lc * 40 + l4 * 4)      = pp[u][jt4 * 2];
                *(uint2*)(pb + lc * 40 + 16 + l4 * 4) = pp[u][jt4 * 2 + 1];
                bf16x8 pfrag = *(bf16x8*)(pb + lc * 40 + l4 * 8);
                bf16x8 va = *(bf16x8*)(vT_lds + vswz(hh[u] * 32 + lc,      jt4 * 32 + l4 * 8));
                bf16x8 vb = *(bf16x8*)(vT_lds + vswz(hh[u] * 32 + 16 + lc, jt4 * 32 + l4 * 8));
                o0 = __builtin_amdgcn_mfma_f32_16x16x32_bf16(va, pfrag, o0, 0, 0, 0);
                o1 = __builtin_amdgcn_mfma_f32_16x16x32_bf16(vb, pfrag, o1, 0, 0, 0);
            }
            const float inv = 1.0f / ls[u];
            uint2 h0, h1;
            h0.x = cvt2(o0[0] * inv, o0[1] * inv); h0.y = cvt2(o0[2] * inv, o0[3] * inv);
            h1.x = cvt2(o1[0] * inv, o1[1] * inv); h1.y = cvt2(o1[2] * inv, o1[3] * inv);
            *(uint2*)(xo_lds + swz(ii[u], hh[u] * 32 + l4 * 4)) = h0;
            *(uint2*)(xo_lds + swz(ii[u], hh[u] * 32 + 16 + l4 * 4)) = h1;
        }
    }
    __syncthreads();

    // ---- Phase 3: y^T = Wproj @ O^T. wave -> ct = wv>>1, token half by wv&1 ----
    {
        const int ct = wv >> 1;
        bf16x8 pw[4];
#pragma unroll
        for (int kt = 0; kt < 4; ++kt)
            pw[kt] = *(const bf16x8*)(wproj + (ct * 16 + lc) * 128 + kt * 32 + l4 * 8);
        f32x4 pbias;
#pragma unroll
        for (int r = 0; r < 4; ++r) pbias[r] = proj_b[ct * 16 + l4 * 4 + r];

        float* ob = out + (size_t)b * 12544;
        const int t0 = (wv & 1) ? 4 : 0, t1 = (wv & 1) ? 7 : 4;
        for (int t = t0; t < t1; ++t) {
            f32x4 acc = pbias;
#pragma unroll
            for (int kt = 0; kt < 4; ++kt) {
                bf16x8 of = *(bf16x8*)(xo_lds + swz(t * 16 + lc, kt * 32 + l4 * 8));
                acc = __builtin_amdgcn_mfma_f32_16x16x32_bf16(pw[kt], of, acc, 0, 0, 0);
            }
            int tok = t * 16 + lc;
            if (tok < 98) {
                float4 st; st.x = acc[0]; st.y = acc[1]; st.z = acc[2]; st.w = acc[3];
                *(float4*)(ob + tok * 128 + ct * 16 + l4 * 4) = st;
            }
        }
    }
}

extern "C" void kernel_launch(void* const* d_in, const int* in_sizes, int n_in,
                              void* d_out, int out_size, void* d_ws, size_t ws_size,
                              hipStream_t stream) {
    const float* x       = (const float*)d_in[0];
    const float* qkv_w   = (const float*)d_in[1];
    const float* qkv_b   = (const float*)d_in[2];
    const float* rpb_tab = (const float*)d_in[3];
    const float* proj_w  = (const float*)d_in[4];
    const float* proj_b  = (const float*)d_in[5];
    const int*   rel_idx = (const int*)d_in[6];
    // d_in[7] (mask) unused: reproduced analytically into the tables.

    unsigned short* wqkv  = (unsigned short*)d_ws;                   // 384*128 bf16 (98304 B)
    unsigned short* wproj = (unsigned short*)((char*)d_ws + 98304);  // 128*128 bf16 (32768 B)
    void*           btab  = (void*)((char*)d_ws + 131072);           // bias table
    float*          out   = (float*)d_out;

    const bool big = ws_size >= (size_t)(131072 + 32 * 112 * 112 * 4);  // 1,736,704 B
    const int LDS_BYTES = 159744;

    if (big) {
        hipLaunchKernelGGL((prep_kernel<true>), dim3(512), dim3(256), 0, stream,
                           qkv_w, proj_w, rpb_tab, rel_idx, wqkv, wproj, btab);
        (void)hipFuncSetAttribute((const void*)(swin_main<true>),
                                  hipFuncAttributeMaxDynamicSharedMemorySize, LDS_BYTES);
        hipLaunchKernelGGL((swin_main<true>), dim3(2048), dim3(1024), LDS_BYTES, stream,
                           x, qkv_b, proj_b, wqkv, wproj, btab, out);
    } else {
        hipLaunchKernelGGL((prep_kernel<false>), dim3(512), dim3(256), 0, stream,
                           qkv_w, proj_w, rpb_tab, rel_idx, wqkv, wproj, btab);
        (void)hipFuncSetAttribute((const void*)(swin_main<false>),
                                  hipFuncAttributeMaxDynamicSharedMemorySize, LDS_BYTES);
        hipLaunchKernelGGL((swin_main<false>), dim3(2048), dim3(1024), LDS_BYTES, stream,
                           x, qkv_b, proj_b, wqkv, wproj, btab, out);
    }
}

// Round 6
// 137.943 us; speedup vs baseline: 1.1611x; 1.1611x over previous
//
#include <hip/hip_runtime.h>
#include <math.h>
#include <stdint.h>

// Video Swin shifted-window attention, fully fused, one block per window.
// Round 6: exact R4 structure (best so far, 137us) + ONE change:
//   vT swizzle XOR = (row&7) ^ ((row>>2)&3)
// Bank analysis: bank index depends only on the 16B-chunk index (row stride
// 256B is a multiple of the 128B bank period). PV reads vary row via lc ->
// (row&7) gives 8 chunks (2-way, free). Phase-1 v scalar writes vary row via
// l4 (bits [3:2]) -> add ((row>>2)&3) so writes also spread (4x2 chunks,
// ~2 lanes/bank). Both sides conflict-free.

#define LOG2E   1.4426950408889634f
#define MASKNEG (-144.26950408889634f)   // -100 * LOG2E

typedef __attribute__((ext_vector_type(8))) short bf16x8;
typedef __attribute__((ext_vector_type(4))) float f32x4;

__device__ __forceinline__ unsigned short cvt1(float f) {
    __bf16 h = (__bf16)f;
    return __builtin_bit_cast(unsigned short, h);
}
__device__ __forceinline__ unsigned cvt2(float lo, float hi) {
    return (unsigned)cvt1(lo) | ((unsigned)cvt1(hi) << 16);
}

// token region code for the shifted-window mask (WIN=(2,7,7), SHIFT=(1,3,3))
__device__ __forceinline__ int tok_code(int t) {
    int pd = t / 49;
    int r  = t - pd * 49;
    int ph = r / 7;
    int pw = r - ph * 7;
    return (pd >= 1 ? 1 : 0) | (ph >= 4 ? 2 : 0) | (pw >= 4 ? 4 : 0);
}

__device__ __forceinline__ float mterm(unsigned pk, int sh, unsigned ci, unsigned cls) {
    return ((((pk >> sh) & 255u) ^ ci) & cls) ? MASKNEG : 0.f;
}

// XOR-swizzled element offset, [rows][128]-bf16 tiles (16B chunks): q/k/xo
__device__ __forceinline__ int swz(int row, int col) {
    return row * 128 + (((col >> 3) ^ (row & 7)) << 3) + (col & 7);
}
// vT swizzle: entropy from row bits [2:0] (reads, lc) AND [3:2] (writes, l4)
__device__ __forceinline__ int vswz(int row, int col) {
    return row * 128 + ((((col >> 3) ^ (row & 7) ^ ((row >> 2) & 3)) & 15) << 3) + (col & 7);
}

// ---------------- prep: weights -> bf16, bias tables ----------------
template<bool BIG>
__global__ void prep_kernel(const float* __restrict__ qkv_w,
                            const float* __restrict__ proj_w,
                            const float* __restrict__ rpb_table,
                            const int*   __restrict__ rel_index,
                            unsigned short* __restrict__ wqkv,
                            unsigned short* __restrict__ wproj,
                            void* __restrict__ btab) {
    int tid = blockIdx.x * blockDim.x + threadIdx.x;
    int stride = gridDim.x * blockDim.x;
    for (int i = tid; i < 384 * 128; i += stride) wqkv[i]  = cvt1(qkv_w[i]);
    for (int i = tid; i < 128 * 128; i += stride) wproj[i] = cvt1(proj_w[i]);
    if constexpr (BIG) {
        // bm[cls 8][h 4][i 112][j 112] f32: (bias + mask)*LOG2E; j>=98 -> -inf
        float* bm = (float*)btab;
        for (int idx = tid; idx < 32 * 112 * 112; idx += stride) {
            int ch = idx / 12544; int r = idx - ch * 12544;
            int i  = r / 112;     int j = r - i * 112;
            int cls = ch >> 2, h = ch & 3;
            float v;
            if (i < 98) {
                if (j < 98) {
                    float bias = rpb_table[rel_index[i * 98 + j] * 4 + h];
                    bool  msk  = (((unsigned)tok_code(i) ^ (unsigned)tok_code(j)) & (unsigned)cls) != 0;
                    v = bias * LOG2E + (msk ? MASKNEG : 0.f);
                } else v = -INFINITY;
            } else v = 0.f;
            bm[idx] = v;
        }
    } else {
        unsigned short* biasL = (unsigned short*)btab;
        for (int idx = tid; idx < 4 * 112 * 112; idx += stride) {
            int h = idx / 12544; int r = idx - h * 12544;
            int i = r / 112;     int j = r - i * 112;
            float v;
            if (i < 98) v = (j < 98) ? rpb_table[rel_index[i * 98 + j] * 4 + h] * LOG2E
                                     : -INFINITY;
            else v = 0.f;
            biasL[idx] = cvt1(v);
        }
    }
}

// ---------------- main fused kernel ----------------
template<bool BIG>
__global__ __launch_bounds__(1024)
void swin_main(const float* __restrict__ x,
               const float* __restrict__ qkv_b,
               const float* __restrict__ proj_b,
               const unsigned short* __restrict__ wqkv,
               const unsigned short* __restrict__ wproj,
               const void* __restrict__ btab,
               float* __restrict__ out)
{
    extern __shared__ unsigned short lds[];
    unsigned short* q_lds  = lds;            // [112][128] bf16, swz
    unsigned short* k_lds  = lds + 14336;    // [112][128] swz
    unsigned short* vT_lds = lds + 28672;    // [128][128] vswz (cols 112..127 zero)
    unsigned short* xo_lds = lds + 45056;    // [112][128] swz; x then O
    unsigned short* p_lds  = lds + 59392;    // [16 waves][2 buf][16][40]

    const int b    = blockIdx.x;
    const int tid  = threadIdx.x;
    const int wv   = tid >> 6;    // 0..15
    const int lane = tid & 63;
    const int l4   = lane >> 4;   // 0..3
    const int lc   = lane & 15;   // 0..15

    // zero vT pad cols 112..127 (128 rows x 16 cols = 2048 ushorts, 2/thread)
    {
        int idx2 = tid * 2;
        int row  = idx2 >> 4;
        int c    = 112 + (idx2 & 15);
        *(unsigned int*)(vT_lds + vswz(row, c)) = 0u;
    }

    // stage x -> xo_lds as bf16 (pad rows 98..111 zeroed)
    {
        const float* xb = x + (size_t)b * 12544;
        for (int idx = tid; idx < 3584; idx += 1024) {
            int tok = idx >> 5;
            int c   = (idx & 31) << 2;
            float4 v;
            if (tok < 98) v = *(const float4*)(xb + tok * 128 + c);
            else { v.x = 0.f; v.y = 0.f; v.z = 0.f; v.w = 0.f; }
            uint2 hv; hv.x = cvt2(v.x, v.y); hv.y = cvt2(v.z, v.w);
            *(uint2*)(xo_lds + swz(tok, c)) = hv;
        }
    }
    __syncthreads();

    // ---- Phase 1: QKV' = Wqkv @ X^T ----
    // wave wv: column-tile ct=wv (q: 0..7 w/ scale, k: 8..15), plus half of a v tile.
    {
        const int ct = wv;
        bf16x8 wf[4];
        f32x4  bias;
        const unsigned short* wrow = wqkv + (ct * 16 + lc) * 128;
#pragma unroll
        for (int kt = 0; kt < 4; ++kt) wf[kt] = *(const bf16x8*)(wrow + kt * 32 + l4 * 8);
#pragma unroll
        for (int r = 0; r < 4; ++r) bias[r] = qkv_b[ct * 16 + l4 * 4 + r];
        const bool  isq = (ct < 8);
        const float qs  = 0.17677669529663689f * LOG2E;  // scale*log2e folded into q
#pragma unroll
        for (int t = 0; t < 7; ++t) {
            bf16x8 xf[4];
#pragma unroll
            for (int kt = 0; kt < 4; ++kt)
                xf[kt] = *(bf16x8*)(xo_lds + swz(t * 16 + lc, kt * 32 + l4 * 8));
            f32x4 acc = bias;
#pragma unroll
            for (int kt = 0; kt < 4; ++kt)
                acc = __builtin_amdgcn_mfma_f32_16x16x32_bf16(wf[kt], xf[kt], acc, 0, 0, 0);
            int tok = t * 16 + lc;
            if (isq) {
                uint2 hv; hv.x = cvt2(acc[0] * qs, acc[1] * qs); hv.y = cvt2(acc[2] * qs, acc[3] * qs);
                *(uint2*)(q_lds + swz(tok, ct * 16 + l4 * 4)) = hv;
            } else {
                uint2 hv; hv.x = cvt2(acc[0], acc[1]); hv.y = cvt2(acc[2], acc[3]);
                *(uint2*)(k_lds + swz(tok, (ct - 8) * 16 + l4 * 4)) = hv;
            }
        }
        // v: wave pair (wv>>1) owns channel block vd, halves split by wv&1
        const int vd = (wv >> 1) * 16;
        bf16x8 wf2[4];
        const unsigned short* wrow2 = wqkv + (256 + vd + lc) * 128;
#pragma unroll
        for (int kt = 0; kt < 4; ++kt) wf2[kt] = *(const bf16x8*)(wrow2 + kt * 32 + l4 * 8);
        f32x4 bias2;
#pragma unroll
        for (int r = 0; r < 4; ++r) bias2[r] = qkv_b[256 + vd + l4 * 4 + r];
        const int t0 = (wv & 1) ? 4 : 0, t1 = (wv & 1) ? 7 : 4;
        for (int t = t0; t < t1; ++t) {
            bf16x8 xf[4];
#pragma unroll
            for (int kt = 0; kt < 4; ++kt)
                xf[kt] = *(bf16x8*)(xo_lds + swz(t * 16 + lc, kt * 32 + l4 * 8));
            f32x4 acc = bias2;
#pragma unroll
            for (int kt = 0; kt < 4; ++kt)
                acc = __builtin_amdgcn_mfma_f32_16x16x32_bf16(wf2[kt], xf[kt], acc, 0, 0, 0);
            int tok = t * 16 + lc;
            const int rb = vd + l4 * 4;
            vT_lds[vswz(rb + 0, tok)] = cvt1(acc[0]);
            vT_lds[vswz(rb + 1, tok)] = cvt1(acc[1]);
            vT_lds[vswz(rb + 2, tok)] = cvt1(acc[2]);
            vT_lds[vswz(rb + 3, tok)] = cvt1(acc[3]);
        }
    }
    __syncthreads();

    // ---- Phase 2: attention. 28 tasks (head,i-tile) over 16 waves, 2 passes ----
    const int wi  = b & 255;
    const unsigned int cls =
        ((wi >> 6) == 3 ? 1u : 0u) | (((wi >> 3) & 7) == 7 ? 2u : 0u) | ((wi & 7) == 7 ? 4u : 0u);

    unsigned int jcp[7];   // packed region codes (small path only)
    if constexpr (!BIG) {
#pragma unroll
        for (int jt = 0; jt < 7; ++jt) {
            int jb = jt * 16 + l4 * 4;
            unsigned int p = 0;
#pragma unroll
            for (int r = 0; r < 4; ++r) p |= (unsigned)tok_code(jb + r < 98 ? jb + r : 0) << (8 * r);
            jcp[jt] = p;
        }
    }

    unsigned short* myP = p_lds + wv * 1280;   // [2][16][40]

    for (int pass = 0; pass < 2; ++pass) {
        int task = wv + (pass << 4);
        if (task >= 28) break;
        int h  = task / 7;
        int it = task - h * 7;
        const int i_tok = it * 16 + lc;
        const bf16x8 qfrag = *(bf16x8*)(q_lds + swz(i_tok, h * 32 + l4 * 8));

        // prefetch all 7 C-operands (bias+mask) into regs so loads overlap
        f32x4 cvec[7];
        if constexpr (BIG) {
            const float* bmrow = (const float*)btab + ((size_t)((int)cls * 4 + h) * 112 + i_tok) * 112;
#pragma unroll
            for (int jt = 0; jt < 7; ++jt)
                cvec[jt] = *(const f32x4*)(bmrow + jt * 16 + l4 * 4);
        } else {
            const unsigned short* brow = (const unsigned short*)btab + (h * 112 + i_tok) * 112;
            const unsigned int ci = (unsigned)tok_code(i_tok < 98 ? i_tok : 0);
            ushort4 bb[7];
#pragma unroll
            for (int jt = 0; jt < 7; ++jt)
                bb[jt] = *(const ushort4*)(brow + jt * 16 + l4 * 4);
#pragma unroll
            for (int jt = 0; jt < 7; ++jt) {
                cvec[jt][0] = __builtin_bit_cast(float, (unsigned)bb[jt].x << 16) + mterm(jcp[jt], 0,  ci, cls);
                cvec[jt][1] = __builtin_bit_cast(float, (unsigned)bb[jt].y << 16) + mterm(jcp[jt], 8,  ci, cls);
                cvec[jt][2] = __builtin_bit_cast(float, (unsigned)bb[jt].z << 16) + mterm(jcp[jt], 16, ci, cls);
                cvec[jt][3] = __builtin_bit_cast(float, (unsigned)bb[jt].w << 16) + mterm(jcp[jt], 24, ci, cls);
            }
        }

        f32x4 s[7];
#pragma unroll
        for (int jt = 0; jt < 7; ++jt) {
            bf16x8 kfrag = *(bf16x8*)(k_lds + swz(jt * 16 + lc, h * 32 + l4 * 8));
            s[jt] = __builtin_amdgcn_mfma_f32_16x16x32_bf16(kfrag, qfrag, cvec[jt], 0, 0, 0);
        }

        // row max (rows of S^T live across l4 groups): tree + shfl 16/32
        float m = -INFINITY;
#pragma unroll
        for (int jt = 0; jt < 7; ++jt)
            m = fmaxf(m, fmaxf(fmaxf(s[jt][0], s[jt][1]), fmaxf(s[jt][2], s[jt][3])));
        m = fmaxf(m, __shfl_xor(m, 16));
        m = fmaxf(m, __shfl_xor(m, 32));

        float lsum = 0.f;
        f32x4 o0 = {0.f, 0.f, 0.f, 0.f}, o1 = {0.f, 0.f, 0.f, 0.f};
#pragma unroll
        for (int jt4 = 0; jt4 < 4; ++jt4) {
            unsigned short* pb = myP + (jt4 & 1) * 640;
#pragma unroll
            for (int sub = 0; sub < 2; ++sub) {
                int jt = jt4 * 2 + sub;       // 0..7; jt==7 is the j=112..127 pad
                uint2 pv;
                if (jt < 7) {
                    float p0 = exp2f(s[jt][0] - m);
                    float p1 = exp2f(s[jt][1] - m);
                    float p2 = exp2f(s[jt][2] - m);
                    float p3 = exp2f(s[jt][3] - m);
                    lsum += (p0 + p1) + (p2 + p3);
                    pv.x = cvt2(p0, p1); pv.y = cvt2(p2, p3);
                } else {
                    pv.x = 0u; pv.y = 0u;
                }
                *(uint2*)(pb + lc * 40 + sub * 16 + l4 * 4) = pv;
            }
            bf16x8 pfrag = *(bf16x8*)(pb + lc * 40 + l4 * 8);
            bf16x8 va = *(bf16x8*)(vT_lds + vswz(h * 32 + lc,      jt4 * 32 + l4 * 8));
            bf16x8 vb = *(bf16x8*)(vT_lds + vswz(h * 32 + 16 + lc, jt4 * 32 + l4 * 8));
            o0 = __builtin_amdgcn_mfma_f32_16x16x32_bf16(va, pfrag, o0, 0, 0, 0);
            o1 = __builtin_amdgcn_mfma_f32_16x16x32_bf16(vb, pfrag, o1, 0, 0, 0);
        }
        lsum += __shfl_xor(lsum, 16);
        lsum += __shfl_xor(lsum, 32);

        float inv = 1.0f / lsum;
        uint2 h0, h1;
        h0.x = cvt2(o0[0] * inv, o0[1] * inv); h0.y = cvt2(o0[2] * inv, o0[3] * inv);
        h1.x = cvt2(o1[0] * inv, o1[1] * inv); h1.y = cvt2(o1[2] * inv, o1[3] * inv);
        *(uint2*)(xo_lds + swz(i_tok, h * 32 + l4 * 4)) = h0;
        *(uint2*)(xo_lds + swz(i_tok, h * 32 + 16 + l4 * 4)) = h1;
    }
    __syncthreads();

    // ---- Phase 3: y^T = Wproj @ O^T. wave -> ct = wv>>1, token half by wv&1 ----
    {
        const int ct = wv >> 1;
        bf16x8 pw[4];
#pragma unroll
        for (int kt = 0; kt < 4; ++kt)
            pw[kt] = *(const bf16x8*)(wproj + (ct * 16 + lc) * 128 + kt * 32 + l4 * 8);
        f32x4 pbias;
#pragma unroll
        for (int r = 0; r < 4; ++r) pbias[r] = proj_b[ct * 16 + l4 * 4 + r];

        float* ob = out + (size_t)b * 12544;
        const int t0 = (wv & 1) ? 4 : 0, t1 = (wv & 1) ? 7 : 4;
        for (int t = t0; t < t1; ++t) {
            f32x4 acc = pbias;
#pragma unroll
            for (int kt = 0; kt < 4; ++kt) {
                bf16x8 of = *(bf16x8*)(xo_lds + swz(t * 16 + lc, kt * 32 + l4 * 8));
                acc = __builtin_amdgcn_mfma_f32_16x16x32_bf16(pw[kt], of, acc, 0, 0, 0);
            }
            int tok = t * 16 + lc;
            if (tok < 98) {
                float4 st; st.x = acc[0]; st.y = acc[1]; st.z = acc[2]; st.w = acc[3];
                *(float4*)(ob + tok * 128 + ct * 16 + l4 * 4) = st;
            }
        }
    }
}

extern "C" void kernel_launch(void* const* d_in, const int* in_sizes, int n_in,
                              void* d_out, int out_size, void* d_ws, size_t ws_size,
                              hipStream_t stream) {
    const float* x       = (const float*)d_in[0];
    const float* qkv_w   = (const float*)d_in[1];
    const float* qkv_b   = (const float*)d_in[2];
    const float* rpb_tab = (const float*)d_in[3];
    const float* proj_w  = (const float*)d_in[4];
    const float* proj_b  = (const float*)d_in[5];
    const int*   rel_idx = (const int*)d_in[6];
    // d_in[7] (mask) unused: reproduced analytically into the tables.

    unsigned short* wqkv  = (unsigned short*)d_ws;                   // 384*128 bf16 (98304 B)
    unsigned short* wproj = (unsigned short*)((char*)d_ws + 98304);  // 128*128 bf16 (32768 B)
    void*           btab  = (void*)((char*)d_ws + 131072);           // bias table
    float*          out   = (float*)d_out;

    const bool big = ws_size >= (size_t)(131072 + 32 * 112 * 112 * 4);  // 1,736,704 B
    const int LDS_BYTES = 159744;

    if (big) {
        hipLaunchKernelGGL((prep_kernel<true>), dim3(512), dim3(256), 0, stream,
                           qkv_w, proj_w, rpb_tab, rel_idx, wqkv, wproj, btab);
        (void)hipFuncSetAttribute((const void*)(swin_main<true>),
                                  hipFuncAttributeMaxDynamicSharedMemorySize, LDS_BYTES);
        hipLaunchKernelGGL((swin_main<true>), dim3(2048), dim3(1024), LDS_BYTES, stream,
                           x, qkv_b, proj_b, wqkv, wproj, btab, out);
    } else {
        hipLaunchKernelGGL((prep_kernel<false>), dim3(512), dim3(256), 0, stream,
                           qkv_w, proj_w, rpb_tab, rel_idx, wqkv, wproj, btab);
        (void)hipFuncSetAttribute((const void*)(swin_main<false>),
                                  hipFuncAttributeMaxDynamicSharedMemorySize, LDS_BYTES);
        hipLaunchKernelGGL((swin_main<false>), dim3(2048), dim3(1024), LDS_BYTES, stream,
                           x, qkv_b, proj_b, wqkv, wproj, btab, out);
    }
}